// Round 8
// baseline (95.401 us; speedup 1.0000x reference)
//
#include <hip/hip_runtime.h>

#define E_ 15000
#define D_ 200
#define L_ 64
#define B_ 256
#define LOG2E 1.4426950408889634f

typedef float v4f __attribute__((ext_vector_type(4)));

// ws layout (chunk-contiguous: chunk c = b's [8c, 8c+8), 32 chunks):
//   qtc @ 0      : [32][200][8] f32  qtc[c][d][bb] = emb_e[e1,d]*emb_rel[rel,d]
//   suc @ 204800 : [32][64][8]  f32  (lit[e1,l]-c[l])*r[l]
//   wtc @ 270336 : [32][64][8]  f32  nfw[rel,l]
//   r   @ 335872 : [64] f32          sqrt(log2e/var[l])
#define QTC_OFF 0
#define SUC_OFF 204800
#define WTC_OFF 270336
#define R_OFF   335872

__global__ __launch_bounds__(256) void setup_k(
    const float* __restrict__ emb_e, const float* __restrict__ emb_rel,
    const float* __restrict__ nfw,   const float* __restrict__ lit,
    const float* __restrict__ c,     const float* __restrict__ var,
    const int* __restrict__ e1,      const int* __restrict__ rel,
    float* __restrict__ qtc, float* __restrict__ suc,
    float* __restrict__ wtc, float* __restrict__ r)
{
    const int b = blockIdx.x;
    const int t = threadIdx.x;
    const int ie = e1[b];
    const int ir = rel[b];
    const int cb = (b >> 3);          // chunk 0..31
    const int bb = (b & 7);
    if (t < D_) qtc[cb * 1600 + t * 8 + bb] =
        emb_e[ie * D_ + t] * emb_rel[ir * D_ + t];
    if (t < L_) {
        const float rl = sqrtf(LOG2E / var[t]);
        suc[cb * 512 + t * 8 + bb] = (lit[ie * L_ + t] - c[t]) * rl;
        wtc[cb * 512 + t * 8 + bb] = nfw[ir * L_ + t];
        if (b == 0) r[t] = rl;
    }
}

// 1888 blocks = 59 e-tiles x 32 b-chunks (BT=8); 256 threads, lane -> e.
// 7.4 waves/SIMD (2x R7's TLP). Per-block 10.7KB LDS staging; inner loops:
// ds_read_b128 broadcast + v_pk_fma_f32 + v_exp_f32, zero VMEM.
__global__ __launch_bounds__(256) void main_k(
    const float* __restrict__ emb_e, const float* __restrict__ lit,
    const float* __restrict__ qtc,   const float* __restrict__ suc,
    const float* __restrict__ wtc,   const float* __restrict__ r,
    float* __restrict__ out)
{
    __shared__ float qt_s[1600];   // 6.4 KB [d][8]
    __shared__ float su_s[512];    // 2.0 KB [l][8]
    __shared__ float wt_s[512];    // 2.0 KB [l][8]
    __shared__ float r_s[64];

    // Bijective XCD swizzle: 1888 = 8*236 exact. Each XCD: 236 consecutive
    // origs = ~7.4 e-tiles (1.9 MB emb_e/lit) re-swept 32x from its L2.
    const int w    = blockIdx.x;
    const int orig = (w & 7) * 236 + (w >> 3);
    const int x = orig >> 5;        // e-tile 0..58
    const int y = orig & 31;        // b-chunk 0..31

    const int tid = threadIdx.x;
    const int e   = x * 256 + tid;
    const int ec  = (e < E_) ? e : (E_ - 1);
    const int b0  = y * 8;

    // ---- one-time coalesced staging: 10.7 KB L2 -> LDS ----
    {
        const float4* qsrc = (const float4*)qtc + y * 400;
        float4* qdst = (float4*)qt_s;
        qdst[tid] = qsrc[tid];
        if (tid < 144) qdst[256 + tid] = qsrc[256 + tid];
        if (tid < 128) {
            ((float4*)su_s)[tid] = ((const float4*)suc)[y * 128 + tid];
            ((float4*)wt_s)[tid] = ((const float4*)wtc)[y * 128 + tid];
        }
        if (tid < 16) ((float4*)r_s)[tid] = ((const float4*)r)[tid];
    }
    __syncthreads();

    v4f acc[2];
    acc[0] = (v4f)(0.0f);
    acc[1] = (v4f)(0.0f);

    // ---- structural: acc[bb] += emb_e[ec,d] * qt_s[d][bb] ----
    const float* ep = emb_e + (size_t)ec * D_;   // rows 16B aligned
    #pragma unroll 2
    for (int d = 0; d < D_; d += 4) {
        const float4 v4 = *(const float4*)(ep + d);
        const float va[4] = {v4.x, v4.y, v4.z, v4.w};
        #pragma unroll
        for (int k = 0; k < 4; ++k) {
            const v4f* q4 = (const v4f*)(qt_s + (d + k) * 8);  // 2x ds_read_b128
            const v4f ev = {va[k], va[k], va[k], va[k]};
            acc[0] = __builtin_elementwise_fma(ev, q4[0], acc[0]);
            acc[1] = __builtin_elementwise_fma(ev, q4[1], acc[1]);
        }
    }

    // ---- RBF: acc[bb] += exp2(-(su_s[l][bb] - lit[ec,l]*r[l])^2) * wt_s[l][bb] ----
    const float* lp = lit + (size_t)ec * L_;     // rows 256B aligned
    #pragma unroll 2
    for (int l = 0; l < L_; l += 4) {
        const float4 x4 = *(const float4*)(lp + l);
        const float xa[4] = {x4.x, x4.y, x4.z, x4.w};
        #pragma unroll
        for (int k = 0; k < 4; ++k) {
            const float u = xa[k] * r_s[l + k];
            const v4f uv = {u, u, u, u};
            const v4f* s4 = (const v4f*)(su_s + (l + k) * 8);
            const v4f* w4 = (const v4f*)(wt_s + (l + k) * 8);
            #pragma unroll
            for (int j = 0; j < 2; ++j) {
                const v4f t = s4[j] - uv;
                const v4f m = -(t * t);
                const v4f ph = {__builtin_amdgcn_exp2f(m.x),
                                __builtin_amdgcn_exp2f(m.y),
                                __builtin_amdgcn_exp2f(m.z),
                                __builtin_amdgcn_exp2f(m.w)};
                acc[j] = __builtin_elementwise_fma(ph, w4[j], acc[j]);
            }
        }
    }

    // ---- sigmoid + coalesced store (1KB contiguous per bb-row) ----
    if (e < E_) {
        #pragma unroll
        for (int j = 0; j < 2; ++j) {
            #pragma unroll
            for (int h = 0; h < 4; ++h) {
                const float z = acc[j][h];
                const float ezn = __builtin_amdgcn_exp2f(-z * LOG2E);
                out[(size_t)(b0 + 4 * j + h) * E_ + e] =
                    __builtin_amdgcn_rcpf(1.0f + ezn);
            }
        }
    }
}

extern "C" void kernel_launch(void* const* d_in, const int* in_sizes, int n_in,
                              void* d_out, int out_size, void* d_ws, size_t ws_size,
                              hipStream_t stream) {
    const float* emb_e   = (const float*)d_in[0];
    const float* emb_rel = (const float*)d_in[1];
    const float* nfw     = (const float*)d_in[2];
    const float* lit     = (const float*)d_in[3];
    const float* c       = (const float*)d_in[4];
    const float* var     = (const float*)d_in[5];
    const int*   e1      = (const int*)d_in[6];
    const int*   rel     = (const int*)d_in[7];
    float* out = (float*)d_out;

    char* ws = (char*)d_ws;
    float* qtc = (float*)(ws + QTC_OFF);
    float* suc = (float*)(ws + SUC_OFF);
    float* wtc = (float*)(ws + WTC_OFF);
    float* r   = (float*)(ws + R_OFF);

    setup_k<<<dim3(B_), dim3(256), 0, stream>>>(emb_e, emb_rel, nfw, lit, c, var,
                                                e1, rel, qtc, suc, wtc, r);

    main_k<<<dim3(1888), dim3(256), 0, stream>>>(emb_e, lit, qtc, suc, wtc, r, out);
}

// Round 10
// 82.526 us; speedup vs baseline: 1.1560x; 1.1560x over previous
//
#include <hip/hip_runtime.h>

#define E_ 15000
#define D_ 200
#define L_ 64
#define B_ 256
#define LOG2E 1.4426950408889634f

typedef float v4f __attribute__((ext_vector_type(4)));

// ws layout (chunk-contiguous: chunk c = b's [16c, 16c+16)):
//   qtc @ 0      : [16][200][16] f32  qtc[c][d][bb] = emb_e[e1,d]*emb_rel[rel,d]
//   suc @ 204800 : [16][64][16]  f32  (lit[e1,l]-c[l])*r[l]
//   wtc @ 270336 : [16][64][16]  f32  nfw[rel,l]
//   r   @ 335872 : [64] f32           sqrt(log2e/var[l])
#define QTC_OFF 0
#define SUC_OFF 204800
#define WTC_OFF 270336
#define R_OFF   335872

__global__ __launch_bounds__(256) void setup_k(
    const float* __restrict__ emb_e, const float* __restrict__ emb_rel,
    const float* __restrict__ nfw,   const float* __restrict__ lit,
    const float* __restrict__ c,     const float* __restrict__ var,
    const int* __restrict__ e1,      const int* __restrict__ rel,
    float* __restrict__ qtc, float* __restrict__ suc,
    float* __restrict__ wtc, float* __restrict__ r)
{
    const int b = blockIdx.x;
    const int t = threadIdx.x;
    const int ie = e1[b];
    const int ir = rel[b];
    const int cb = (b >> 4);
    const int bb = (b & 15);
    if (t < D_) qtc[cb * 3200 + t * 16 + bb] =
        emb_e[ie * D_ + t] * emb_rel[ir * D_ + t];
    if (t < L_) {
        const float rl = sqrtf(LOG2E / var[t]);
        suc[cb * 1024 + t * 16 + bb] = (lit[ie * L_ + t] - c[t]) * rl;
        wtc[cb * 1024 + t * 16 + bb] = nfw[ir * L_ + t];
        if (b == 0) r[t] = rl;
    }
}

// 944 blocks = 59 e-tiles x 16 b-chunks (R7 skeleton, proven 10MB fetch).
// Software-pipelined register prefetch of the e-row streams (4 float4 in
// flight structural, 2 float4 RBF) + b128 LDS reads + v4f packed math.
// R9 bug fixed: RBF prefetch tail now loads l=56..63 (was reloading 48..55).
__global__ __launch_bounds__(256, 2) void main_k(
    const float* __restrict__ emb_e, const float* __restrict__ lit,
    const float* __restrict__ qtc,   const float* __restrict__ suc,
    const float* __restrict__ wtc,   const float* __restrict__ r,
    float* __restrict__ out)
{
    __shared__ float qt_s[3200];   // 12.8 KB [d][16]
    __shared__ float su_s[1024];   //  4.0 KB [l][16]
    __shared__ float wt_s[1024];   //  4.0 KB [l][16]
    __shared__ float r_s[64];

    // Bijective XCD swizzle: 944 = 8*118 exact.
    const int w    = blockIdx.x;
    const int orig = (w & 7) * 118 + (w >> 3);
    const int x = orig >> 4;        // e-tile 0..58
    const int y = orig & 15;        // b-chunk 0..15

    const int tid = threadIdx.x;
    const int e   = x * 256 + tid;
    const int ec  = (e < E_) ? e : (E_ - 1);
    const int b0  = y * 16;

    // ---- one-time coalesced staging: 21 KB L2 -> LDS ----
    {
        const float4* qsrc = (const float4*)qtc + y * 800;
        float4* qdst = (float4*)qt_s;
        #pragma unroll
        for (int i = 0; i < 3; ++i) qdst[tid + 256 * i] = qsrc[tid + 256 * i];
        if (tid < 32) qdst[768 + tid] = qsrc[768 + tid];
        ((float4*)su_s)[tid] = ((const float4*)suc)[y * 256 + tid];
        ((float4*)wt_s)[tid] = ((const float4*)wtc)[y * 256 + tid];
        if (tid < 16) ((float4*)r_s)[tid] = ((const float4*)r)[tid];
    }
    __syncthreads();

    v4f acc[4];
    #pragma unroll
    for (int j = 0; j < 4; ++j) acc[j] = (v4f)(0.0f);

    const float* ep = emb_e + (size_t)ec * D_;   // rows 16B aligned (800B)
    const float* lp = lit + (size_t)ec * L_;     // rows 256B aligned

    // consume 4 d's from a float4 against qt_s
    #define DO_D4(F4, DBASE)                                                   \
        {                                                                      \
            const float va_[4] = {(F4).x, (F4).y, (F4).z, (F4).w};             \
            _Pragma("unroll")                                                  \
            for (int k = 0; k < 4; ++k) {                                      \
                const v4f* q4_ = (const v4f*)(qt_s + ((DBASE) + k) * 16);      \
                const v4f ev_ = {va_[k], va_[k], va_[k], va_[k]};              \
                acc[0] = __builtin_elementwise_fma(ev_, q4_[0], acc[0]);       \
                acc[1] = __builtin_elementwise_fma(ev_, q4_[1], acc[1]);       \
                acc[2] = __builtin_elementwise_fma(ev_, q4_[2], acc[2]);       \
                acc[3] = __builtin_elementwise_fma(ev_, q4_[3], acc[3]);       \
            }                                                                  \
        }

    // ---- structural: chunks of 16 d, 4 float4 prefetched one chunk ahead ----
    {
        float4 buf[4], nxt[4];
        #pragma unroll
        for (int i = 0; i < 4; ++i) buf[i] = ((const float4*)ep)[i];
        #pragma unroll 1
        for (int dc = 0; dc <= 160; dc += 16) {          // 11 iters: 0..160
            #pragma unroll
            for (int i = 0; i < 4; ++i)
                nxt[i] = ((const float4*)(ep + dc + 16))[i];
            #pragma unroll
            for (int i = 0; i < 4; ++i) DO_D4(buf[i], dc + 4 * i);
            #pragma unroll
            for (int i = 0; i < 4; ++i) buf[i] = nxt[i];
        }
        // buf now holds d=176..191
        #pragma unroll
        for (int i = 0; i < 4; ++i) DO_D4(buf[i], 176 + 4 * i);
        // tail d=192..199
        float4 t0 = ((const float4*)(ep + 192))[0];
        float4 t1 = ((const float4*)(ep + 196))[0];
        DO_D4(t0, 192);
        DO_D4(t1, 196);
    }

    // consume 4 l's from a float4 against su_s/wt_s
    #define DO_L4(F4, LBASE)                                                   \
        {                                                                      \
            const float xa_[4] = {(F4).x, (F4).y, (F4).z, (F4).w};             \
            _Pragma("unroll")                                                  \
            for (int k = 0; k < 4; ++k) {                                      \
                const int l_ = (LBASE) + k;                                    \
                const float u_ = xa_[k] * r_s[l_];                             \
                const v4f uv_ = {u_, u_, u_, u_};                              \
                const v4f* s4_ = (const v4f*)(su_s + l_ * 16);                 \
                const v4f* w4_ = (const v4f*)(wt_s + l_ * 16);                 \
                _Pragma("unroll")                                              \
                for (int j = 0; j < 4; ++j) {                                  \
                    const v4f t_ = s4_[j] - uv_;                               \
                    const v4f m_ = -(t_ * t_);                                 \
                    const v4f ph_ = {__builtin_amdgcn_exp2f(m_.x),             \
                                     __builtin_amdgcn_exp2f(m_.y),             \
                                     __builtin_amdgcn_exp2f(m_.z),             \
                                     __builtin_amdgcn_exp2f(m_.w)};            \
                    acc[j] = __builtin_elementwise_fma(ph_, w4_[j], acc[j]);   \
                }                                                              \
            }                                                                  \
        }

    // ---- RBF: chunks of 8 l, 2 float4 prefetched one chunk ahead ----
    {
        float4 lb[2], ln[2];
        #pragma unroll
        for (int i = 0; i < 2; ++i) lb[i] = ((const float4*)lp)[i];
        #pragma unroll 1
        for (int lc = 0; lc <= 48; lc += 8) {            // 7 iters: 0..48
            // prefetch lc+8; at lc=48 that's l=56..63 (in bounds, L=64)
            #pragma unroll
            for (int i = 0; i < 2; ++i)
                ln[i] = ((const float4*)(lp + lc + 8))[i];
            DO_L4(lb[0], lc);
            DO_L4(lb[1], lc + 4);
            #pragma unroll
            for (int i = 0; i < 2; ++i) lb[i] = ln[i];
        }
        // lb now holds l=56..63
        DO_L4(lb[0], 56);
        DO_L4(lb[1], 60);
    }

    // ---- sigmoid + coalesced store (1KB contiguous per bb-row) ----
    if (e < E_) {
        #pragma unroll
        for (int j = 0; j < 4; ++j) {
            #pragma unroll
            for (int h = 0; h < 4; ++h) {
                const float z = acc[j][h];
                const float ezn = __builtin_amdgcn_exp2f(-z * LOG2E);
                out[(size_t)(b0 + 4 * j + h) * E_ + e] =
                    __builtin_amdgcn_rcpf(1.0f + ezn);
            }
        }
    }
}

extern "C" void kernel_launch(void* const* d_in, const int* in_sizes, int n_in,
                              void* d_out, int out_size, void* d_ws, size_t ws_size,
                              hipStream_t stream) {
    const float* emb_e   = (const float*)d_in[0];
    const float* emb_rel = (const float*)d_in[1];
    const float* nfw     = (const float*)d_in[2];
    const float* lit     = (const float*)d_in[3];
    const float* c       = (const float*)d_in[4];
    const float* var     = (const float*)d_in[5];
    const int*   e1      = (const int*)d_in[6];
    const int*   rel     = (const int*)d_in[7];
    float* out = (float*)d_out;

    char* ws = (char*)d_ws;
    float* qtc = (float*)(ws + QTC_OFF);
    float* suc = (float*)(ws + SUC_OFF);
    float* wtc = (float*)(ws + WTC_OFF);
    float* r   = (float*)(ws + R_OFF);

    setup_k<<<dim3(B_), dim3(256), 0, stream>>>(emb_e, emb_rel, nfw, lit, c, var,
                                                e1, rel, qtc, suc, wtc, r);

    main_k<<<dim3(944), dim3(256), 0, stream>>>(emb_e, lit, qtc, suc, wtc, r, out);
}

// Round 12
// 72.260 us; speedup vs baseline: 1.3202x; 1.1421x over previous
//
#include <hip/hip_runtime.h>

#define E_ 15000
#define D_ 200
#define L_ 64
#define B_ 256
#define LOG2E 1.4426950408889634f

typedef float v2f __attribute__((ext_vector_type(2)));
typedef float v4f __attribute__((ext_vector_type(4)));

#define LO2(q) __builtin_shufflevector(q, q, 0, 1)
#define HI2(q) __builtin_shufflevector(q, q, 2, 3)

// acc = a * b + acc — packed f32; ALL operands are VGPR pairs (VOP3P rule).
__device__ __forceinline__ void pk_fma(v2f& acc, v2f a, v2f b) {
    asm("v_pk_fma_f32 %0, %1, %2, %0"
        : "+v"(acc) : "v"(a), "v"(b));
}
// d = a * b + c
__device__ __forceinline__ v2f pk_fma3(v2f a, v2f b, v2f c) {
    v2f d;
    asm("v_pk_fma_f32 %0, %1, %2, %3"
        : "=v"(d) : "v"(a), "v"(b), "v"(c));
    return d;
}

// ws layout (chunk-contiguous: chunk c = b's [16c, 16c+16)):
//   qtc @ 0      : [16][200][16] f32  qtc[c][d][bb] = emb_e[e1,d]*emb_rel[rel,d]
//   suc @ 204800 : [16][64][16]  f32  su2 = 2*(lit[e1,l]-c[l])*r[l]
//   wtc @ 270336 : [16][64][16]  f32  w'  = nfw[rel,l]*exp2(-su^2)
//   r   @ 335872 : [64] f32           r[l] = sqrt(log2e/var[l])
// RBF factorization: -(su-u)^2 = 2*su*u - u^2 - su^2 with u = lit[e,l]*r[l];
// phi*wt = w' * exp2(su2*u - u^2).
#define QTC_OFF 0
#define SUC_OFF 204800
#define WTC_OFF 270336
#define R_OFF   335872

__global__ __launch_bounds__(256) void setup_k(
    const float* __restrict__ emb_e, const float* __restrict__ emb_rel,
    const float* __restrict__ nfw,   const float* __restrict__ lit,
    const float* __restrict__ c,     const float* __restrict__ var,
    const int* __restrict__ e1,      const int* __restrict__ rel,
    float* __restrict__ qtc, float* __restrict__ suc,
    float* __restrict__ wtc, float* __restrict__ r)
{
    const int b = blockIdx.x;
    const int t = threadIdx.x;
    const int ie = e1[b];
    const int ir = rel[b];
    const int cb = (b >> 4);
    const int bb = (b & 15);
    if (t < D_) qtc[cb * 3200 + t * 16 + bb] =
        emb_e[ie * D_ + t] * emb_rel[ir * D_ + t];
    if (t < L_) {
        const float rl = sqrtf(LOG2E / var[t]);
        const float su = (lit[ie * L_ + t] - c[t]) * rl;
        suc[cb * 1024 + t * 16 + bb] = 2.0f * su;
        wtc[cb * 1024 + t * 16 + bb] = nfw[ir * L_ + t] * exp2f(-su * su);
        if (b == 0) r[t] = rl;
    }
}

// 944 blocks = 59 e-tiles x 16 b-chunks (R7 skeleton: 10MB fetch, no spills).
// vs R7: forced v_pk_fma_f32 (all-pair operands) + factored RBF.
__global__ __launch_bounds__(256) void main_k(
    const float* __restrict__ emb_e, const float* __restrict__ lit,
    const float* __restrict__ qtc,   const float* __restrict__ suc,
    const float* __restrict__ wtc,   const float* __restrict__ r,
    float* __restrict__ out)
{
    __shared__ float qt_s[3200];   // 12.8 KB [d][16]
    __shared__ float su_s[1024];   //  4.0 KB [l][16]  (su2)
    __shared__ float wt_s[1024];   //  4.0 KB [l][16]  (w')
    __shared__ float r_s[64];

    // Bijective XCD swizzle: 944 = 8*118 exact.
    const int w    = blockIdx.x;
    const int orig = (w & 7) * 118 + (w >> 3);
    const int x = orig >> 4;        // e-tile 0..58
    const int y = orig & 15;        // b-chunk 0..15

    const int tid = threadIdx.x;
    const int e   = x * 256 + tid;
    const int ec  = (e < E_) ? e : (E_ - 1);
    const int b0  = y * 16;

    // ---- one-time coalesced staging: 21 KB L2 -> LDS ----
    {
        const float4* qsrc = (const float4*)qtc + y * 800;
        float4* qdst = (float4*)qt_s;
        #pragma unroll
        for (int i = 0; i < 3; ++i) qdst[tid + 256 * i] = qsrc[tid + 256 * i];
        if (tid < 32) qdst[768 + tid] = qsrc[768 + tid];
        ((float4*)su_s)[tid] = ((const float4*)suc)[y * 256 + tid];
        ((float4*)wt_s)[tid] = ((const float4*)wtc)[y * 256 + tid];
        if (tid < 16) ((float4*)r_s)[tid] = ((const float4*)r)[tid];
    }
    __syncthreads();

    v2f acc2[8];
    #pragma unroll
    for (int j = 0; j < 8; ++j) acc2[j] = (v2f)(0.0f);

    // ---- structural: acc[bb] += emb_e[ec,d] * qt_s[d][bb]  (v_pk_fma_f32) ----
    const float* ep = emb_e + (size_t)ec * D_;   // rows 16B aligned (800B)
    #pragma unroll 2
    for (int d = 0; d < D_; d += 4) {
        const float4 v4 = *(const float4*)(ep + d);
        const float va[4] = {v4.x, v4.y, v4.z, v4.w};
        #pragma unroll
        for (int k = 0; k < 4; ++k) {
            const v2f ev = {va[k], va[k]};               // broadcast pair (1 mov / 8 FMA)
            const v4f* qrow = (const v4f*)(qt_s + (d + k) * 16);
            #pragma unroll
            for (int g = 0; g < 4; ++g) {
                const v4f q = qrow[g];
                pk_fma(acc2[2 * g],     LO2(q), ev);
                pk_fma(acc2[2 * g + 1], HI2(q), ev);
            }
        }
    }

    // ---- RBF (factored): acc[bb] += w'[l][bb] * exp2(su2[l][bb]*u - u^2) ----
    const float* lp = lit + (size_t)ec * L_;     // rows 256B aligned
    #pragma unroll 2
    for (int l = 0; l < L_; l += 4) {
        const float4 x4 = *(const float4*)(lp + l);
        const float xa[4] = {x4.x, x4.y, x4.z, x4.w};
        #pragma unroll
        for (int k = 0; k < 4; ++k) {
            const float u   = xa[k] * r_s[l + k];
            const float u2n = -u * u;
            const v2f uv   = {u, u};                     // 2 movs / 16 elems
            const v2f u2nv = {u2n, u2n};
            const v4f* srow = (const v4f*)(su_s + (l + k) * 16);
            const v4f* wrow = (const v4f*)(wt_s + (l + k) * 16);
            #pragma unroll
            for (int g = 0; g < 4; ++g) {
                const v4f s4 = srow[g];
                const v4f w4 = wrow[g];
                const v2f a0 = pk_fma3(LO2(s4), uv, u2nv);
                const v2f a1 = pk_fma3(HI2(s4), uv, u2nv);
                v2f ph0, ph1;
                ph0.x = __builtin_amdgcn_exp2f(a0.x);
                ph0.y = __builtin_amdgcn_exp2f(a0.y);
                ph1.x = __builtin_amdgcn_exp2f(a1.x);
                ph1.y = __builtin_amdgcn_exp2f(a1.y);
                pk_fma(acc2[2 * g],     ph0, LO2(w4));
                pk_fma(acc2[2 * g + 1], ph1, HI2(w4));
            }
        }
    }

    // ---- sigmoid + coalesced store (1KB contiguous per bb-row) ----
    if (e < E_) {
        #pragma unroll
        for (int j = 0; j < 8; ++j) {
            #pragma unroll
            for (int h = 0; h < 2; ++h) {
                const float z = h ? acc2[j].y : acc2[j].x;
                const float ezn = __builtin_amdgcn_exp2f(-z * LOG2E);
                out[(size_t)(b0 + 2 * j + h) * E_ + e] =
                    __builtin_amdgcn_rcpf(1.0f + ezn);
            }
        }
    }
}

extern "C" void kernel_launch(void* const* d_in, const int* in_sizes, int n_in,
                              void* d_out, int out_size, void* d_ws, size_t ws_size,
                              hipStream_t stream) {
    const float* emb_e   = (const float*)d_in[0];
    const float* emb_rel = (const float*)d_in[1];
    const float* nfw     = (const float*)d_in[2];
    const float* lit     = (const float*)d_in[3];
    const float* c       = (const float*)d_in[4];
    const float* var     = (const float*)d_in[5];
    const int*   e1      = (const int*)d_in[6];
    const int*   rel     = (const int*)d_in[7];
    float* out = (float*)d_out;

    char* ws = (char*)d_ws;
    float* qtc = (float*)(ws + QTC_OFF);
    float* suc = (float*)(ws + SUC_OFF);
    float* wtc = (float*)(ws + WTC_OFF);
    float* r   = (float*)(ws + R_OFF);

    setup_k<<<dim3(B_), dim3(256), 0, stream>>>(emb_e, emb_rel, nfw, lit, c, var,
                                                e1, rel, qtc, suc, wtc, r);

    main_k<<<dim3(944), dim3(256), 0, stream>>>(emb_e, lit, qtc, suc, wtc, r, out);
}